// Round 3
// baseline (27614.609 us; speedup 1.0000x reference)
//
#include <hip/hip_runtime.h>
#include <hip/hip_fp16.h>
#include <stdint.h>
#include <stddef.h>

typedef _Float16 f16;
typedef _Float16 f16x8 __attribute__((ext_vector_type(8)));
typedef float f32x4 __attribute__((ext_vector_type(4)));

#define SEQL 512
#define NBATCH 64
#define KIN 38
#define KPAD 64
#define EMB 1024
#define HID 1024
#define G3 3072
#define MALL (SEQL*NBATCH)   // 32768
#define NCLS 38

// ---------------- conversion / prep kernels ----------------

__global__ void k_cvt(const float* __restrict__ s, f16* __restrict__ d, long n) {
  long i = (long)blockIdx.x * blockDim.x + threadIdx.x;
  long stride = (long)gridDim.x * blockDim.x;
  for (; i < n; i += stride) d[i] = (f16)s[i];
}

__global__ void k_outw_pad(const float* __restrict__ s, f16* __restrict__ d) {
  int i = blockIdx.x * 256 + threadIdx.x;   // 128*1024
  if (i >= 128 * 1024) return;
  int r = i >> 10, c = i & 1023;
  d[i] = (r < NCLS) ? (f16)s[r * 1024 + c] : (f16)0.f;
}

__global__ void k_cvt_in(const float* __restrict__ s, f16* __restrict__ d) {
  int i = blockIdx.x * 256 + threadIdx.x;   // 32768*64
  if (i >= MALL * KPAD) return;
  int m = i >> 6, k = i & 63;
  d[i] = (k < KIN) ? (f16)s[m * KIN + k] : (f16)0.f;
}

// W0[g][k] = sum_e w_ih0[g][e] * emb_W[e][k]   (fold embedding into layer-0 proj)
__global__ void k_prep_w0(const float* __restrict__ wih0, const float* __restrict__ embW,
                          f16* __restrict__ w0) {
  int i = blockIdx.x * 256 + threadIdx.x;   // 3072*64
  if (i >= G3 * KPAD) return;
  int g = i >> 6, k = i & 63;
  float sacc = 0.f;
  if (k < KIN) {
    for (int e = 0; e < EMB; ++e) sacc += wih0[g * EMB + e] * embW[e * KIN + k];
  }
  w0[i] = (f16)sacc;
}

// b0[g] = b_ih0[g] + sum_e w_ih0[g][e] * emb_b[e]
__global__ void k_prep_b0(const float* __restrict__ wih0, const float* __restrict__ embB,
                          const float* __restrict__ bih0, float* __restrict__ b0) {
  int g = blockIdx.x * 256 + threadIdx.x;
  if (g >= G3) return;
  float sacc = bih0[g];
  for (int e = 0; e < EMB; ++e) sacc += wih0[g * EMB + e] * embB[e];
  b0[g] = sacc;
}

// ---------------- main GEMM: C = A @ B^T + bias  (fp16 in, fp16 or fp32 out) ----------------
// A: [M][K] row-major fp16, B: [N][K] row-major fp16. 128x128 tile, 4 waves,
// each wave a 64x64 quadrant = 4x4 tiles of mfma_f32_16x16x32_f16.

__global__ __launch_bounds__(256) void k_gemm(
    const f16* __restrict__ A, const f16* __restrict__ B,
    const float* __restrict__ bias,
    f16* __restrict__ C16, float* __restrict__ C32,
    int K, int nvalid, int ldc) {
  __shared__ f16 As[128][40];   // +8 pad: bank-conflict-friendly, keeps 16B align
  __shared__ f16 Bs[128][40];
  const int tid = threadIdx.x;
  const long brow = (long)blockIdx.x * 128;
  const long bcol = (long)blockIdx.y * 128;
  const int w = tid >> 6, lane = tid & 63;
  const int lr = lane & 15, kg = lane >> 4;
  const int wr = w >> 1, wc = w & 1;

  f32x4 acc[4][4] = {};

  for (int kk = 0; kk < K; kk += 32) {
    __syncthreads();
#pragma unroll
    for (int p = 0; p < 2; ++p) {
      int idx = p * 256 + tid;          // 0..511 -> 128 rows x 4 segs of 16B
      int row = idx >> 2, seg = idx & 3;
      *(float4*)(&As[row][seg * 8]) = *(const float4*)(&A[(brow + row) * K + kk + seg * 8]);
      *(float4*)(&Bs[row][seg * 8]) = *(const float4*)(&B[(bcol + row) * K + kk + seg * 8]);
    }
    __syncthreads();
    f16x8 af[4], bf[4];
#pragma unroll
    for (int i = 0; i < 4; ++i) af[i] = *(const f16x8*)(&As[wr * 64 + i * 16 + lr][kg * 8]);
#pragma unroll
    for (int j = 0; j < 4; ++j) bf[j] = *(const f16x8*)(&Bs[wc * 64 + j * 16 + lr][kg * 8]);
#pragma unroll
    for (int i = 0; i < 4; ++i)
#pragma unroll
      for (int j = 0; j < 4; ++j)
        acc[i][j] = __builtin_amdgcn_mfma_f32_16x16x32_f16(af[i], bf[j], acc[i][j], 0, 0, 0);
  }

#pragma unroll
  for (int j = 0; j < 4; ++j) {
    int col = (int)bcol + wc * 64 + j * 16 + lr;
    float bv = (col < nvalid) ? bias[col] : 0.f;
#pragma unroll
    for (int i = 0; i < 4; ++i) {
#pragma unroll
      for (int r = 0; r < 4; ++r) {
        long row = brow + wr * 64 + i * 16 + kg * 4 + r;
        float v = acc[i][j][r] + bv;
        if (C16) C16[row * ldc + col] = (f16)v;
        else if (col < nvalid) C32[row * ldc + col] = v;
      }
    }
  }
}

// ---------------- GRU step: one launch per timestep ----------------
// Block g owns hidden slice j0=g*16 (16 units -> gate cols j0, 1024+j0, 2048+j0).
// Wave w handles batch rows 16w..16w+15. hg = h_{t-1} @ w_hh^T via 3 MFMAs/K-chunk,
// then gates elementwise in-register (D-layout: col=lane&15, row=(lane>>4)*4+r).

__global__ __launch_bounds__(256) void k_step(
    const f16* __restrict__ hprev,   // [64][1024] or nullptr (t==0 -> h=0)
    const f16* __restrict__ xgt,     // [64][3072]  (includes b_ih)
    const f16* __restrict__ whhl,    // [3072][1024]
    const float* __restrict__ bhhl,  // [3072]
    f16* __restrict__ hout) {        // [64][1024]
  const int g = blockIdx.x;          // 0..63
  const int j0 = g * 16;
  const int tid = threadIdx.x;
  const int w = tid >> 6, lane = tid & 63;
  const int lr = lane & 15, kg = lane >> 4;

  f32x4 ar = {}, az = {}, an = {};
  if (hprev) {
    const f16* ha  = hprev + (16 * w + lr) * HID;
    const f16* wr_ = whhl + (size_t)(j0 + lr) * HID;
    const f16* wz_ = whhl + (size_t)(1024 + j0 + lr) * HID;
    const f16* wn_ = whhl + (size_t)(2048 + j0 + lr) * HID;
#pragma unroll 4
    for (int kk = 0; kk < 32; ++kk) {
      int off = kk * 32 + kg * 8;
      f16x8 a = *(const f16x8*)(ha + off);
      ar = __builtin_amdgcn_mfma_f32_16x16x32_f16(a, *(const f16x8*)(wr_ + off), ar, 0, 0, 0);
      az = __builtin_amdgcn_mfma_f32_16x16x32_f16(a, *(const f16x8*)(wz_ + off), az, 0, 0, 0);
      an = __builtin_amdgcn_mfma_f32_16x16x32_f16(a, *(const f16x8*)(wn_ + off), an, 0, 0, 0);
    }
  }
  const int j = j0 + lr;
  const float br = bhhl[j], bz = bhhl[1024 + j], bn = bhhl[2048 + j];
#pragma unroll
  for (int r = 0; r < 4; ++r) {
    int m = 16 * w + kg * 4 + r;
    float xr = (float)xgt[m * G3 + j];
    float xz = (float)xgt[m * G3 + 1024 + j];
    float xn = (float)xgt[m * G3 + 2048 + j];
    float hp = hprev ? (float)hprev[m * HID + j] : 0.f;
    float rr = 1.f / (1.f + __expf(-(xr + ar[r] + br)));
    float zz = 1.f / (1.f + __expf(-(xz + az[r] + bz)));
    float pre = xn + rr * (an[r] + bn);
    float nn = 2.f / (1.f + __expf(-2.f * pre)) - 1.f;   // tanh
    hout[m * HID + j] = (f16)((1.f - zz) * nn + zz * hp);
  }
}

// ---------------- launch ----------------

extern "C" void kernel_launch(void* const* d_in, const int* in_sizes, int n_in,
                              void* d_out, int out_size, void* d_ws, size_t ws_size,
                              hipStream_t stream) {
  const float* in   = (const float*)d_in[0];
  const float* embW = (const float*)d_in[1];
  const float* embB = (const float*)d_in[2];
  const float* wih  = (const float*)d_in[3];
  const float* whh  = (const float*)d_in[4];
  const float* bih  = (const float*)d_in[5];
  const float* bhh  = (const float*)d_in[6];
  const float* outW = (const float*)d_in[7];
  const float* outB = (const float*)d_in[8];
  float* out = (float*)d_out;

  char* ws = (char*)d_ws;
  size_t off = 0;
  auto alloc = [&](size_t bytes) -> void* {
    void* p = ws + off; off += (bytes + 255) & ~(size_t)255; return p;
  };
  // fixed-footprint allocations (~85 MB total)
  f16* whhL   = (f16*)alloc((size_t)G3 * HID * 2);    // 6 MB, re-converted per layer
  f16* wihL   = (f16*)alloc((size_t)G3 * HID * 2);    // 6 MB, layers 1,2
  f16* w016   = (f16*)alloc((size_t)G3 * KPAD * 2);   // 0.4 MB
  f16* outw16 = (f16*)alloc(128UL * HID * 2);         // 0.26 MB
  float* b0   = (float*)alloc((size_t)G3 * 4);        // 12 KB
  f16* in16   = (f16*)alloc((size_t)MALL * KPAD * 2); // 4 MB
  f16* xseq   = (f16*)alloc((size_t)MALL * HID * 2);  // 64 MB, in-place across layers
  size_t fixed = off;

  // choose timestep chunk T from remaining workspace (constant across calls)
  int T = 128;
  while (T > 2 && fixed + ((size_t)T * NBATCH * G3 * 2 + 256) > ws_size) T >>= 1;
  f16* xg = (f16*)alloc((size_t)T * NBATCH * G3 * 2);
  if (off > ws_size) return;   // nothing sane possible
  const int NCHUNK = SEQL / T;

  // ---- prep (every call: ws is re-poisoned) ----
  k_outw_pad<<<512, 256, 0, stream>>>(outW, outw16);
  k_cvt_in<<<(MALL * KPAD + 255) / 256, 256, 0, stream>>>(in, in16);
  k_prep_w0<<<(G3 * KPAD + 255) / 256, 256, 0, stream>>>(wih, embW, w016);
  k_prep_b0<<<(G3 + 255) / 256, 256, 0, stream>>>(wih, embB, bih, b0);

  for (int l = 0; l < 3; ++l) {
    // convert this layer's recurrent (and input, l>=1) weights
    k_cvt<<<2048, 256, 0, stream>>>(whh + (size_t)l * G3 * HID, whhL, (long)G3 * HID);
    if (l > 0)
      k_cvt<<<2048, 256, 0, stream>>>(wih + (size_t)l * G3 * EMB, wihL, (long)G3 * HID);

    for (int c = 0; c < NCHUNK; ++c) {
      // xg = x_chunk @ W^T + b for T timesteps (layer 0: folded embedding, K=64)
      if (l == 0)
        k_gemm<<<dim3(T * NBATCH / 128, G3 / 128), 256, 0, stream>>>(
            in16 + (size_t)c * T * NBATCH * KPAD, w016, b0, xg, nullptr, KPAD, G3, G3);
      else
        k_gemm<<<dim3(T * NBATCH / 128, G3 / 128), 256, 0, stream>>>(
            xseq + (size_t)c * T * NBATCH * HID, wihL, bih + l * G3, xg, nullptr, HID, G3, G3);
      // recurrence: T sequential step launches; outputs overwrite xseq rows in place
      for (int t = 0; t < T; ++t) {
        int gt = c * T + t;
        k_step<<<64, 256, 0, stream>>>(
            gt ? xseq + (size_t)(gt - 1) * NBATCH * HID : nullptr,
            xg + (size_t)t * NBATCH * G3,
            whhL, bhh + l * G3,
            xseq + (size_t)gt * NBATCH * HID);
      }
    }
  }
  // logits = xseq @ out_W^T + out_b  (fp32 out, cols<38 stored)
  k_gemm<<<dim3(MALL / 128, 1), 256, 0, stream>>>(xseq, outw16, outB, nullptr, out,
                                                  HID, NCLS, NCLS);
}

// Round 4
// 16480.389 us; speedup vs baseline: 1.6756x; 1.6756x over previous
//
#include <hip/hip_runtime.h>
#include <hip/hip_fp16.h>
#include <stdint.h>
#include <stddef.h>

typedef _Float16 f16;
typedef _Float16 f16x8 __attribute__((ext_vector_type(8)));
typedef float f32x4 __attribute__((ext_vector_type(4)));

#define SEQL 512
#define NBATCH 64
#define KIN 38
#define KPAD 64
#define EMB 1024
#define HID 1024
#define G3 3072
#define MALL (SEQL*NBATCH)   // 32768
#define NCLS 38
#define WPAD 1032            // 1024 + 8 f16 pad -> even LDS bank spread

// ---------------- conversion / prep kernels ----------------

__global__ void k_cvt(const float* __restrict__ s, f16* __restrict__ d, long n) {
  long i = (long)blockIdx.x * blockDim.x + threadIdx.x;
  long stride = (long)gridDim.x * blockDim.x;
  for (; i < n; i += stride) d[i] = (f16)s[i];
}

__global__ void k_zero(int* __restrict__ p, int n) {
  int i = blockIdx.x * 256 + threadIdx.x;
  if (i < n) p[i] = 0;
}

__global__ void k_outw_pad(const float* __restrict__ s, f16* __restrict__ d) {
  int i = blockIdx.x * 256 + threadIdx.x;   // 128*1024
  if (i >= 128 * 1024) return;
  int r = i >> 10, c = i & 1023;
  d[i] = (r < NCLS) ? (f16)s[r * 1024 + c] : (f16)0.f;
}

__global__ void k_cvt_in(const float* __restrict__ s, f16* __restrict__ d) {
  int i = blockIdx.x * 256 + threadIdx.x;   // 32768*64
  if (i >= MALL * KPAD) return;
  int m = i >> 6, k = i & 63;
  d[i] = (k < KIN) ? (f16)s[m * KIN + k] : (f16)0.f;
}

// W0[g][k] = sum_e w_ih0[g][e] * emb_W[e][k]   (fold embedding into layer-0 proj)
__global__ void k_prep_w0(const float* __restrict__ wih0, const float* __restrict__ embW,
                          f16* __restrict__ w0) {
  int i = blockIdx.x * 256 + threadIdx.x;   // 3072*64
  if (i >= G3 * KPAD) return;
  int g = i >> 6, k = i & 63;
  float sacc = 0.f;
  if (k < KIN) {
    for (int e = 0; e < EMB; ++e) sacc += wih0[g * EMB + e] * embW[e * KIN + k];
  }
  w0[i] = (f16)sacc;
}

// b0[g] = b_ih0[g] + sum_e w_ih0[g][e] * emb_b[e]
__global__ void k_prep_b0(const float* __restrict__ wih0, const float* __restrict__ embB,
                          const float* __restrict__ bih0, float* __restrict__ b0) {
  int g = blockIdx.x * 256 + threadIdx.x;
  if (g >= G3) return;
  float sacc = bih0[g];
  for (int e = 0; e < EMB; ++e) sacc += wih0[g * EMB + e] * embB[e];
  b0[g] = sacc;
}

// ---------------- main GEMM: C = A @ B^T + bias  (fp16 in, fp16 or fp32 out) ----------------

__global__ __launch_bounds__(256) void k_gemm(
    const f16* __restrict__ A, const f16* __restrict__ B,
    const float* __restrict__ bias,
    f16* __restrict__ C16, float* __restrict__ C32,
    int K, int nvalid, int ldc) {
  __shared__ f16 As[128][40];
  __shared__ f16 Bs[128][40];
  const int tid = threadIdx.x;
  const long brow = (long)blockIdx.x * 128;
  const long bcol = (long)blockIdx.y * 128;
  const int w = tid >> 6, lane = tid & 63;
  const int lr = lane & 15, kg = lane >> 4;
  const int wr = w >> 1, wc = w & 1;

  f32x4 acc[4][4] = {};

  for (int kk = 0; kk < K; kk += 32) {
    __syncthreads();
#pragma unroll
    for (int p = 0; p < 2; ++p) {
      int idx = p * 256 + tid;
      int row = idx >> 2, seg = idx & 3;
      *(float4*)(&As[row][seg * 8]) = *(const float4*)(&A[(brow + row) * K + kk + seg * 8]);
      *(float4*)(&Bs[row][seg * 8]) = *(const float4*)(&B[(bcol + row) * K + kk + seg * 8]);
    }
    __syncthreads();
    f16x8 af[4], bf[4];
#pragma unroll
    for (int i = 0; i < 4; ++i) af[i] = *(const f16x8*)(&As[wr * 64 + i * 16 + lr][kg * 8]);
#pragma unroll
    for (int j = 0; j < 4; ++j) bf[j] = *(const f16x8*)(&Bs[wc * 64 + j * 16 + lr][kg * 8]);
#pragma unroll
    for (int i = 0; i < 4; ++i)
#pragma unroll
      for (int j = 0; j < 4; ++j)
        acc[i][j] = __builtin_amdgcn_mfma_f32_16x16x32_f16(af[i], bf[j], acc[i][j], 0, 0, 0);
  }

#pragma unroll
  for (int j = 0; j < 4; ++j) {
    int col = (int)bcol + wc * 64 + j * 16 + lr;
    float bv = (col < nvalid) ? bias[col] : 0.f;
#pragma unroll
    for (int i = 0; i < 4; ++i) {
#pragma unroll
      for (int r = 0; r < 4; ++r) {
        long row = brow + wr * 64 + i * 16 + kg * 4 + r;
        float v = acc[i][j][r] + bv;
        if (C16) C16[row * ldc + col] = (f16)v;
        else if (col < nvalid) C32[row * ldc + col] = v;
      }
    }
  }
}

// ---------------- persistent GRU recurrence: T steps per launch ----------------
// 64 blocks (1/CU, co-resident: 99KB LDS). Block g owns hidden cols j0=g*16:
// its 48 w_hh rows (r,z,n) live in LDS for the whole chunk. Per step: 3 MFMAs
// x 32 K-chunks per wave (wave w = batch rows 16w..16w+15), gates in-register,
// then a device-scope atomic grid barrier. h ping-pongs through hbuf[2] with
// per-block-private 2KB slices (layout [kblk][m][k&15]) so no cache line is
// written by two blocks (XCD L2s are not coherent). xseq gets a plain copy of
// h_t as the layer output (read only after kernel end).

__global__ __launch_bounds__(256) void k_rnn(
    f16* __restrict__ xseq,          // [SEQL*64][1024] layer outputs (write rows t0..t0+T)
    f16* __restrict__ hbuf,          // [2][64][64][16] f16 ping-pong
    const f16* __restrict__ xg,      // [T*64][3072] input projections (incl. b_ih)
    const f16* __restrict__ whhl,    // [3072][1024] fp16
    const float* __restrict__ bhhl,  // [3072]
    int t0, int T, int* __restrict__ cnt) {   // cnt[t] zero-initialized, t absolute
  __shared__ f16 wlds[48 * WPAD];    // ~99KB
  const int g = blockIdx.x, j0 = g * 16, tid = threadIdx.x;
  const int w = tid >> 6, lane = tid & 63, lr = lane & 15, kg = lane >> 4;

  // stage 48 weight rows: wlds[gt*16+r][k], global row gt*1024 + j0 + r
  for (int idx = tid; idx < 48 * 128; idx += 256) {
    int row = idx >> 7, seg = idx & 127;
    int gt = row >> 4, r = row & 15;
    *(f16x8*)&wlds[row * WPAD + seg * 8] =
        *(const f16x8*)&whhl[(size_t)((gt << 10) + j0 + r) * HID + seg * 8];
  }
  __syncthreads();

  const int j = j0 + lr;
  const float br = bhhl[j], bz = bhhl[1024 + j], bn = bhhl[2048 + j];
  const f16* wr_ = &wlds[(0 * 16 + lr) * WPAD];
  const f16* wz_ = &wlds[(1 * 16 + lr) * WPAD];
  const f16* wn_ = &wlds[(2 * 16 + lr) * WPAD];

  for (int tt = 0; tt < T; ++tt) {
    const int t = t0 + tt;
    f32x4 ar = {}, az = {}, an = {};
    if (t > 0) {
      // A-frag h[m][k]: hbuf[p^1] + (k>>4)*1024 + m*16 + (k&15), m = 16w+lr
      const f16* hb = hbuf + (((t & 1) ^ 1) ? (size_t)(64 * HID) : 0);
      const f16* hbase = hb + (16 * w + lr) * 16 + (kg & 1) * 8 + (kg >> 1) * 1024;
      const int ko0 = kg * 8;
#pragma unroll 8
      for (int kc = 0; kc < 32; ++kc) {
        f16x8 a = *(const f16x8*)(hbase + kc * 2048);
        int ko = kc * 32 + ko0;
        ar = __builtin_amdgcn_mfma_f32_16x16x32_f16(a, *(const f16x8*)(wr_ + ko), ar, 0, 0, 0);
        az = __builtin_amdgcn_mfma_f32_16x16x32_f16(a, *(const f16x8*)(wz_ + ko), az, 0, 0, 0);
        an = __builtin_amdgcn_mfma_f32_16x16x32_f16(a, *(const f16x8*)(wn_ + ko), an, 0, 0, 0);
      }
    }
    const f16* hbp = hbuf + (((t & 1) ^ 1) ? (size_t)(64 * HID) : 0) + g * 1024;
    f16* hbn = hbuf + ((t & 1) ? (size_t)(64 * HID) : 0) + g * 1024;
    f16* xrow = xseq + (size_t)t * (NBATCH * HID);
    const f16* xgt = xg + (size_t)tt * NBATCH * G3;
#pragma unroll
    for (int r = 0; r < 4; ++r) {
      int m = 16 * w + kg * 4 + r;
      float xr = (float)xgt[m * G3 + j];
      float xz = (float)xgt[m * G3 + 1024 + j];
      float xn = (float)xgt[m * G3 + 2048 + j];
      float hp = (t > 0) ? (float)hbp[m * 16 + lr] : 0.f;
      float rr = 1.f / (1.f + __expf(-(xr + ar[r] + br)));
      float zz = 1.f / (1.f + __expf(-(xz + az[r] + bz)));
      float pre = xn + rr * (an[r] + bn);
      float nn = 2.f / (1.f + __expf(-2.f * pre)) - 1.f;   // tanh
      float hv = (1.f - zz) * nn + zz * hp;
      hbn[m * 16 + lr] = (f16)hv;
      xrow[m * HID + j] = (f16)hv;
    }
    // device-scope grid barrier (64 co-resident blocks)
    __syncthreads();                 // drains vmcnt -> all block stores in L2
    if (tid == 0) {
      __hip_atomic_fetch_add(&cnt[t], 1, __ATOMIC_RELEASE, __HIP_MEMORY_SCOPE_AGENT);
      while (__hip_atomic_load(&cnt[t], __ATOMIC_ACQUIRE, __HIP_MEMORY_SCOPE_AGENT) < 64) {
        __builtin_amdgcn_s_sleep(1);
      }
    }
    __syncthreads();
  }
}

// ---------------- launch ----------------

extern "C" void kernel_launch(void* const* d_in, const int* in_sizes, int n_in,
                              void* d_out, int out_size, void* d_ws, size_t ws_size,
                              hipStream_t stream) {
  const float* in   = (const float*)d_in[0];
  const float* embW = (const float*)d_in[1];
  const float* embB = (const float*)d_in[2];
  const float* wih  = (const float*)d_in[3];
  const float* whh  = (const float*)d_in[4];
  const float* bih  = (const float*)d_in[5];
  const float* bhh  = (const float*)d_in[6];
  const float* outW = (const float*)d_in[7];
  const float* outB = (const float*)d_in[8];
  float* out = (float*)d_out;

  char* ws = (char*)d_ws;
  size_t off = 0;
  auto alloc = [&](size_t bytes) -> void* {
    void* p = ws + off; off += (bytes + 255) & ~(size_t)255; return p;
  };
  f16* whhL   = (f16*)alloc((size_t)G3 * HID * 2);    // 6 MB, re-converted per layer
  f16* wihL   = (f16*)alloc((size_t)G3 * HID * 2);    // 6 MB, layers 1,2
  f16* w016   = (f16*)alloc((size_t)G3 * KPAD * 2);
  f16* outw16 = (f16*)alloc(128UL * HID * 2);
  float* b0   = (float*)alloc((size_t)G3 * 4);
  f16* in16   = (f16*)alloc((size_t)MALL * KPAD * 2); // 4 MB
  f16* xseq   = (f16*)alloc((size_t)MALL * HID * 2);  // 64 MB, in-place across layers
  f16* hbuf   = (f16*)alloc(2UL * NBATCH * HID * 2);  // 256 KB ping-pong
  int* cnt    = (int*)alloc(3UL * SEQL * 4);          // per-(layer,step) barrier counters
  size_t fixed = off;

  int T = 128;
  while (T > 2 && fixed + ((size_t)T * NBATCH * G3 * 2 + 256) > ws_size) T >>= 1;
  f16* xg = (f16*)alloc((size_t)T * NBATCH * G3 * 2);
  if (off > ws_size) return;
  const int NCHUNK = SEQL / T;

  // ---- prep ----
  k_zero<<<(3 * SEQL + 255) / 256, 256, 0, stream>>>(cnt, 3 * SEQL);
  k_outw_pad<<<512, 256, 0, stream>>>(outW, outw16);
  k_cvt_in<<<(MALL * KPAD + 255) / 256, 256, 0, stream>>>(in, in16);
  k_prep_w0<<<(G3 * KPAD + 255) / 256, 256, 0, stream>>>(wih, embW, w016);
  k_prep_b0<<<(G3 + 255) / 256, 256, 0, stream>>>(wih, embB, bih, b0);

  for (int l = 0; l < 3; ++l) {
    k_cvt<<<2048, 256, 0, stream>>>(whh + (size_t)l * G3 * HID, whhL, (long)G3 * HID);
    if (l > 0)
      k_cvt<<<2048, 256, 0, stream>>>(wih + (size_t)l * G3 * EMB, wihL, (long)G3 * HID);

    for (int c = 0; c < NCHUNK; ++c) {
      if (l == 0)
        k_gemm<<<dim3(T * NBATCH / 128, G3 / 128), 256, 0, stream>>>(
            in16 + (size_t)c * T * NBATCH * KPAD, w016, b0, xg, nullptr, KPAD, G3, G3);
      else
        k_gemm<<<dim3(T * NBATCH / 128, G3 / 128), 256, 0, stream>>>(
            xseq + (size_t)c * T * NBATCH * HID, wihL, bih + l * G3, xg, nullptr, HID, G3, G3);
      // persistent recurrence for this chunk (in-place xseq overwrite)
      k_rnn<<<64, 256, 0, stream>>>(xseq, hbuf, xg, whhL, bhh + l * G3,
                                    c * T, T, cnt + l * SEQL);
    }
  }
  // logits
  k_gemm<<<dim3(MALL / 128, 1), 256, 0, stream>>>(xseq, outw16, outB, nullptr, out,
                                                  HID, NCLS, NCLS);
}